// Round 8
// baseline (235.269 us; speedup 1.0000x reference)
//
#include <hip/hip_runtime.h>
#include <stdint.h>

// x: (8, 64, 256, 256) fp32; alpha: (1,64,1,1) fp32
// out = x + alpha[c] * sum_{3x3 zero-padded} |x - neighbor|  (center tap = 0)
//
// R8 = R7's global_load_lds staging (first structure to beat 79us: reads are
// fire-and-forget, no result-VGPR fight with regalloc) + the missing piece:
// DOUBLE-BUFFERED PERSISTENT BLOCKS. R7 blocks were single-shot
// (stage -> drain -> compute -> exit), so co-resident blocks oscillated
// between all-staging and all-computing -> HBM read duty cycle << 1.
// Now each block owns 64 rows = 4 slabs of 16, ping-pong LDS: stage(k+1)
// is issued BEFORE compute(k), so the barrier's implicit vmcnt(0) lands a
// full compute-phase after issue and only catches the tail (T3 2-phase
// minimum template).
// - LDS row = [4 zero dwords][256 data][zero][3 pad], stride 264 dwords:
//   horizontal halo = direct LDS read, no shuffles/cndmask.
// - 2 x 19 KB buffers = 38 KB -> 4 blocks/CU, 16 waves/CU.
// - NT stores: out (134 MB) bypasses L2/L3 so x can stay L3-resident.
// - XCD-aware decode: an image's 4 blocks land on one XCD's L2.

typedef float f32x4 __attribute__((ext_vector_type(4)));

constexpr int H = 256;
constexpr int W = 256;
constexpr int C = 64;
constexpr int SLAB  = 16;           // output rows per stage
constexpr int NR    = SLAB + 2;     // staged rows incl. vertical halo
constexpr int RSTR  = 264;          // LDS row stride in dwords (1056 B)
constexpr int NSLAB = 4;            // slabs per block (64 rows)

typedef const uint32_t __attribute__((address_space(1)))* gas_t;
typedef uint32_t __attribute__((address_space(3)))* las_t;

__device__ __forceinline__ void stage_slab(const float* __restrict__ imgp,
                                           int y0, float* __restrict__ buf,
                                           int wave, int lane)
{
    // Rows g = y0-1 .. y0+16 into buf rows 0..17 (wave-strided).
#pragma unroll
    for (int r = wave; r < NR; r += 4) {
        const int g = y0 + r - 1;
        if (g >= 0 && g < H) {              // wave-uniform
            const float* gsrc = imgp + (long)g * W + lane * 4;
            // LDS dest: wave-uniform base; HW appends lane*16 (m104).
            __builtin_amdgcn_global_load_lds((gas_t)gsrc,
                                             (las_t)&buf[r * RSTR + 4],
                                             16, 0, 0);
        } else {
            // vertical zero-pad (image top/bottom)
            *(f32x4*)&buf[r * RSTR + 4 + lane * 4] =
                (f32x4){0.f, 0.f, 0.f, 0.f};
        }
    }
}

__device__ __forceinline__ void compute_slab(const float* __restrict__ buf,
                                             float* __restrict__ outp,
                                             int y0, float a,
                                             int wave, int lane)
{
    const int r0    = wave * 4 + 1;         // buf row of wave's first output
    const int cbase = 4 + lane * 4;         // dword index of lane's quad

    f32x4 eq[3];                            // rolling 3-row window
    float eL[3], eR[3];
#pragma unroll
    for (int k = 0; k < 2; ++k) {           // rows r0-1, r0
        const int rr = r0 - 1 + k;
        eq[k] = *(const f32x4*)&buf[rr * RSTR + cbase];
        eL[k] = buf[rr * RSTR + cbase - 1]; // lane0 -> pad slot = 0
        eR[k] = buf[rr * RSTR + cbase + 4]; // lane63 -> pad slot = 0
    }

    float* orow0 = outp + (long)(y0 + wave * 4) * W + lane * 4;

#pragma unroll
    for (int o = 0; o < 4; ++o) {
        const int s = (o + 2) % 3, t = o % 3, m = (o + 1) % 3;
        const int rr = r0 + o + 1;          // new bottom window row
        eq[s] = *(const f32x4*)&buf[rr * RSTR + cbase];
        eL[s] = buf[rr * RSTR + cbase - 1];
        eR[s] = buf[rr * RSTR + cbase + 4];

        float e[3][6];
#pragma unroll
        for (int k = 0; k < 3; ++k) {
            const int kk = (k == 0) ? t : ((k == 1) ? m : s);  // const idx
            e[k][0] = eL[kk];
            e[k][1] = eq[kk].x; e[k][2] = eq[kk].y;
            e[k][3] = eq[kk].z; e[k][4] = eq[kk].w;
            e[k][5] = eR[kk];
        }

        f32x4 res;
#pragma unroll
        for (int j = 0; j < 4; ++j) {
            const float xc = e[1][j + 1];
            float sacc = 0.f;
#pragma unroll
            for (int r2 = 0; r2 < 3; ++r2)
#pragma unroll
                for (int d = 0; d < 3; ++d)
                    sacc += fabsf(xc - e[r2][j + d]);   // center adds 0
            res[j] = fmaf(a, sacc, xc);
        }
        __builtin_nontemporal_store(res, (f32x4*)(orow0 + o * W));
    }
}

__global__ __launch_bounds__(256) void adc_kernel(
    const float* __restrict__ x,
    const float* __restrict__ alpha,
    float* __restrict__ out)
{
    __shared__ float lds[2][NR * RSTR];     // 2 * 19,008 B = 38,016 B

    const int tid  = threadIdx.x;
    const int lane = tid & 63;
    const int wave = tid >> 6;              // 0..3

    // Grid 2048 = 8 xcd * 64 img-group * 4 strips. Round-robin dispatch
    // puts n%8 on XCD n%8 -> all 4 strips of an image share one XCD's L2.
    const int n     = blockIdx.x;
    const int xcd   = n & 7;
    const int local = n >> 3;               // 0..255
    const int img   = ((local >> 2) << 3) + xcd;   // 0..511
    const int ybase = (local & 3) * (NSLAB * SLAB); // 0,64,128,192

    const float a = alpha[img & (C - 1)];
    const float* imgp = x   + (long)img * (H * W);
    float*       outp = out + (long)img * (H * W);

    // Zero the horizontal pad slots of both buffers (once).
    if (tid < 2 * NR) {
        float* row = &lds[tid >= NR][(tid % NR) * RSTR];
        *(f32x4*)row = (f32x4){0.f, 0.f, 0.f, 0.f};
        row[260] = 0.f;
    }

    // Prologue: stage slab 0 into buf 0.
    stage_slab(imgp, ybase, &lds[0][0], wave, lane);
    __syncthreads();   // waits vmcnt(0)+lgkmcnt(0): slab0 + pads ready

    // 2-phase pipeline: issue stage(k+1) before compute(k); the barrier's
    // implicit vmcnt(0) drain happens AFTER a full compute phase of flight.
#pragma unroll
    for (int k = 0; k < NSLAB; ++k) {
        if (k + 1 < NSLAB)
            stage_slab(imgp, ybase + (k + 1) * SLAB,
                       &lds[(k + 1) & 1][0], wave, lane);
        compute_slab(&lds[k & 1][0], outp, ybase + k * SLAB, a, wave, lane);
        __syncthreads();
    }
}

extern "C" void kernel_launch(void* const* d_in, const int* in_sizes, int n_in,
                              void* d_out, int out_size, void* d_ws, size_t ws_size,
                              hipStream_t stream)
{
    const float* x     = (const float*)d_in[0];
    const float* alpha = (const float*)d_in[1];
    float*       out   = (float*)d_out;

    const int grid = 8 * C * (H / (NSLAB * SLAB));  // 512 images * 4 = 2048
    adc_kernel<<<grid, 256, 0, stream>>>(x, alpha, out);
}

// Round 9
// 231.353 us; speedup vs baseline: 1.0169x; 1.0169x over previous
//
#include <hip/hip_runtime.h>
#include <stdint.h>

// x: (8, 64, 256, 256) fp32; alpha: (1,64,1,1) fp32
// out = x + alpha[c] * sum_{3x3 zero-padded} |x - neighbor|  (center tap = 0)
//
// R9: BARRIER-FREE wave-private streaming. R8 proved the stall is the
// vmcnt(0) drain inside every __syncthreads coupling waves to just-issued
// staging loads. Fix: each wave owns a 16-row strip + a PRIVATE 8-slot LDS
// ring (1KB rows). It streams: issue global_load_lds for row i=o+6, counted
// s_waitcnt vmcnt(WN) (guarantees row i=o+2 landed; never drains below 8 in
// steady state -> 4 loads + 4 NT stores always in flight), ds_read the new
// row, compute, NT-store. No __syncthreads anywhere (no cross-wave LDS use).
// WN derived from the exact per-wave VMEM stream (loads + stores, in-order
// vmcnt): {4,5,6,7,8*8,7,6,5,4}.
// - Halo columns via __shfl (R8's scalar b32 LDS reads were the 2.38M bank
//   conflicts); vertical pad rows: clamped load + zero-overwrite after the
//   covering wait (keeps VMEM counts uniform).
// - 4 waves * 8KB ring = 32KB/block -> 5 blocks/CU -> 20 async waves/CU.
// - NT stores keep x L3-resident (R8: FETCH=67MB = half of x served by L3).
// - XCD decode: an image's 4 blocks share one XCD's L2.

typedef float f32x4 __attribute__((ext_vector_type(4)));

constexpr int H = 256, W = 256, C = 64;
constexpr int RSTR = 256;            // dwords per ring slot (1 KB row)

typedef const uint32_t __attribute__((address_space(1)))* gas_t;
typedef uint32_t __attribute__((address_space(3)))* las_t;

#define WAITV(n) do { asm volatile("s_waitcnt vmcnt(" #n ")" ::: "memory"); \
                      __builtin_amdgcn_sched_barrier(0); } while (0)

__global__ __launch_bounds__(256) void adc_kernel(
    const float* __restrict__ x,
    const float* __restrict__ alpha,
    float* __restrict__ out)
{
    __shared__ float lds[4 * 8 * RSTR];   // 4 waves x 8-slot ring = 32 KB

    const int tid  = threadIdx.x, lane = tid & 63, wave = tid >> 6;
    const int n    = blockIdx.x, xcd = n & 7, local = n >> 3;
    const int img  = ((local >> 2) << 3) + xcd;          // 0..511
    const int y0   = ((local & 3) * 4 + wave) * 16;      // wave strip start

    const float a = alpha[img & (C - 1)];
    const float* imgp  = x   + (long)img * (H * W);
    float*       outp  = out + (long)img * (H * W);
    float*       wring = lds + wave * 8 * RSTR;

    const f32x4 z4 = {0.f, 0.f, 0.f, 0.f};

    // ---- Prologue: issue loads i=0..5 (rows y0-1 .. y0+4; top clamped,
    //      zero-fixed after the o=0 wait). Slot(i) = i & 7. ----
#pragma unroll
    for (int i = 0; i < 6; ++i) {
        int g = y0 - 1 + i; if (g < 0) g = 0;
        __builtin_amdgcn_global_load_lds(
            (gas_t)(imgp + (long)g * W + lane * 4),
            (las_t)&wring[(i & 7) * RSTR], 16, 0, 0);
    }

    f32x4 m[3]; float eL[3], eR[3];   // rolling 3-row window (const-indexed)

#define READROW(I, K) {                                                  \
        f32x4 f = *(const f32x4*)&wring[((I) & 7) * RSTR + lane * 4];    \
        const float lft = __shfl_up(f.w, 1);                             \
        const float rgt = __shfl_down(f.x, 1);                           \
        m[K]  = f;                                                       \
        eL[K] = (lane == 0)  ? 0.f : lft;   /* w==0 image edge */        \
        eR[K] = (lane == 63) ? 0.f : rgt; } /* w==W image edge */

#define ITER(O, WN_) {                                                   \
        if ((O) < 12) {   /* issue row i = O+6 (g = y0+O+5; bot clamp) */ \
            const int i_ = (O) + 6;                                      \
            int g_ = y0 + i_ - 1; if (g_ > H - 1) g_ = H - 1;            \
            __builtin_amdgcn_global_load_lds(                            \
                (gas_t)(imgp + (long)g_ * W + lane * 4),                 \
                (las_t)&wring[(i_ & 7) * RSTR], 16, 0, 0);               \
        }                                                                \
        WAITV(WN_);     /* row i=O+2 (and all older) now landed */       \
        if ((O) == 0 && y0 == 0)            /* top pad row (i=0) */      \
            *(f32x4*)&wring[0 * RSTR + lane * 4] = z4;                   \
        if ((O) == 15 && y0 + 16 >= H)      /* bottom pad row (i=17) */  \
            *(f32x4*)&wring[(17 & 7) * RSTR + lane * 4] = z4;            \
        if ((O) == 0) { READROW(0, 0) READROW(1, 1) }                    \
        READROW((O) + 2, ((O) + 2) % 3)                                  \
        {                                                                \
            const int t_ = (O) % 3, c_ = ((O)+1) % 3, b_ = ((O)+2) % 3;  \
            float e[3][6];                                               \
            e[0][0]=eL[t_]; e[0][1]=m[t_].x; e[0][2]=m[t_].y;            \
            e[0][3]=m[t_].z; e[0][4]=m[t_].w; e[0][5]=eR[t_];            \
            e[1][0]=eL[c_]; e[1][1]=m[c_].x; e[1][2]=m[c_].y;            \
            e[1][3]=m[c_].z; e[1][4]=m[c_].w; e[1][5]=eR[c_];            \
            e[2][0]=eL[b_]; e[2][1]=m[b_].x; e[2][2]=m[b_].y;            \
            e[2][3]=m[b_].z; e[2][4]=m[b_].w; e[2][5]=eR[b_];            \
            f32x4 res;                                                   \
            _Pragma("unroll")                                            \
            for (int j = 0; j < 4; ++j) {                                \
                const float xc = e[1][j + 1];                            \
                float s = 0.f;                                           \
                _Pragma("unroll")                                        \
                for (int r = 0; r < 3; ++r)                              \
                    _Pragma("unroll")                                    \
                    for (int d = 0; d < 3; ++d)                          \
                        s += fabsf(xc - e[r][j + d]);  /* center adds 0 */\
                res[j] = fmaf(a, s, xc);                                 \
            }                                                            \
            __builtin_nontemporal_store(res,                             \
                (f32x4*)(outp + (long)(y0 + (O)) * W + lane * 4));       \
        } }

    // Per-wave VMEM stream: L0..L5 | L6 W C S0 | L7 W C S1 | ... in-order
    // vmcnt => ops-after-L(O+2) = {4,5,6,7, 8x8, 7,6,5,4}.
    ITER(0, 4)  ITER(1, 5)  ITER(2, 6)  ITER(3, 7)
    ITER(4, 8)  ITER(5, 8)  ITER(6, 8)  ITER(7, 8)
    ITER(8, 8)  ITER(9, 8)  ITER(10, 8) ITER(11, 8)
    ITER(12, 7) ITER(13, 6) ITER(14, 5) ITER(15, 4)

#undef ITER
#undef READROW
}

extern "C" void kernel_launch(void* const* d_in, const int* in_sizes, int n_in,
                              void* d_out, int out_size, void* d_ws, size_t ws_size,
                              hipStream_t stream)
{
    const float* x     = (const float*)d_in[0];
    const float* alpha = (const float*)d_in[1];
    float*       out   = (float*)d_out;

    const int grid = 8 * C * 4;   // 512 images * 4 blocks (4 strips/block)
    adc_kernel<<<grid, 256, 0, stream>>>(x, alpha, out);
}